// Round 6
// baseline (310.038 us; speedup 1.0000x reference)
//
#include <hip/hip_runtime.h>

#define B_ 32
#define N_ 4
#define D_ 128
#define M_ 32768
#define K_ 1024

#define IDX_OFF 16777216
#define LOSS_OFF 16908288
#define PERP_OFF 16908292

// ws float-index layout
#define WS_LOSS 0
#define WS_CNT 1024
#define WS_ENORM 8192
#define WS_BPACK_F 16384       // packed split-bf16 codebook: 4 layers * 512KB = 2MB
#define BPACK_LAYER_US 262144

#define SBIAS 384.0f
#define MARGIN 0.012f

typedef __bf16 bf16x8 __attribute__((ext_vector_type(8)));
typedef float f32x4 __attribute__((ext_vector_type(4)));

union FragU {
  bf16x8 v;
  ushort u16[8];
  uint4 q;
};

__device__ __forceinline__ ushort bf16_hi_rne(float f, float* hif) {
  uint u = __float_as_uint(f);
  uint r = (u + 0x7fffu + ((u >> 16) & 1u)) >> 16;
  *hif = __uint_as_float(r << 16);
  return (ushort)r;
}
__device__ __forceinline__ ushort bf16_rne(float f) {
  uint u = __float_as_uint(f);
  return (ushort)((u + 0x7fffu + ((u >> 16) & 1u)) >> 16);
}

// --- prep: coalesced pack (LDS bounce) + enorm + zero accumulators ---
__global__ __launch_bounds__(256) void vq_pack(const float* __restrict__ cb,
                                               float* __restrict__ ws) {
  __shared__ ushort Hs[16 * 132];
  __shared__ ushort Ls[16 * 132];
  __shared__ float Ps[256];
  int blk = blockIdx.x, tid = threadIdx.x;
  if (blk < 256) {
    int n = blk >> 6, tile = blk & 63;
    // phase 1: coalesced read of 16 codes x 128 d; split to hi/lo in LDS
    int c = tid >> 4, f = tid & 15;
    const float* src = cb + ((size_t)(n * K_ + tile * 16 + c)) * D_ + f * 8;
    float4 v0 = *(const float4*)src;
    float4 v1 = *(const float4*)(src + 4);
    float v[8] = {v0.x, v0.y, v0.z, v0.w, v1.x, v1.y, v1.z, v1.w};
    float ss = 0.f;
#pragma unroll
    for (int j = 0; j < 8; ++j) {
      float hif;
      Hs[c * 132 + f * 8 + j] = bf16_hi_rne(v[j], &hif);
      Ls[c * 132 + f * 8 + j] = bf16_rne(v[j] - hif);
      ss = fmaf(v[j], v[j], ss);
    }
    Ps[c * 16 + f] = ss;
    __syncthreads();
    if (tid < 16) {
      float s = 0.f;
#pragma unroll
      for (int j = 0; j < 16; ++j) s += Ps[tid * 16 + j];
      ws[WS_ENORM + n * K_ + tile * 16 + tid] = SBIAS - 0.5f * s;
    }
    // phase 2: fragment-ordered coalesced write
    int s = tid >> 6, lane = tid & 63;
    int code = lane & 15, dstart = s * 32 + ((lane >> 4) << 3);
    FragU fh, fl;
#pragma unroll
    for (int j = 0; j < 8; ++j) {
      fh.u16[j] = Hs[code * 132 + dstart + j];
      fl.u16[j] = Ls[code * 132 + dstart + j];
    }
    ushort* dst = (ushort*)(ws + WS_BPACK_F) + (size_t)n * BPACK_LAYER_US +
                  ((size_t)(tile * 4 + s) * 2) * 512 + lane * 8;
    *(uint4*)dst = fh.q;
    *(uint4*)(dst + 512) = fl.q;
  } else {
    // zero loss + histogram
#pragma unroll
    for (int i = 0; i < 20; ++i) ws[i * 256 + tid] = 0.f;
  }
}

// --- main: barrier-free K-loop, B fragments direct from L2 ---
__global__ __launch_bounds__(256, 4) void vq_main(const float* __restrict__ x,
                                                  const float* __restrict__ cb,
                                                  float* __restrict__ ws,
                                                  float* __restrict__ out) {
  __shared__ alignas(16) uint Lds[5120];  // 20 KB
  const int tid = threadIdx.x;
  const int bid = blockIdx.x;
  // XCD swizzle: layer n on XCD pair {2n,2n+1} (dispatch round-robin heuristic)
  const int xcd = bid & 7;
  const int n = xcd >> 1;
  const int mblk = (xcd & 1) * 128 + (bid >> 3);
  const int b = mblk >> 3;
  const int hw0 = (mblk & 7) << 7;

  const int lane = tid & 63, w = tid >> 6;
  const int quad = lane >> 4, l15 = lane & 15;

  const float* xbase = x + (size_t)((b * 4 + n) * 128) * 1024 + hw0;
  const float* cbn = cb + (size_t)n * K_ * D_;
  const float* enB = ws + WS_ENORM + n * K_;
  const uint4* gB = (const uint4*)((ushort*)(ws + WS_BPACK_F) + (size_t)n * BPACK_LAYER_US);

  // LDS carve
  uint* sS = Lds;                          // [128][17]
  uint* sS2 = Lds + 2176;                  // [128][17]  (ends 4352)
  int* sIdx = (int*)(Lds + 4352);          // [128]
  float* dist = (float*)(Lds + 4480);      // [128]
  int* list = (int*)(Lds + 4608);          // [128]
  int* lcnt = (int*)(Lds + 4736);          // [1]
  double* xrowd = (double*)(Lds + 4740);   // [128] (8B aligned)
  double* rd = (double*)(Lds + 4996);      // [4]
  int* rk = (int*)(Lds + 5004);            // [4]
  float* Qs = (float*)Lds;                 // [32][128] = 16KB (reused late)

  if (tid == 0) *lcnt = 0;

  // ---- A fragments in registers: 32 rows/wave, 2 sets of 16; + ||x||^2 ----
  bf16x8 ahi[2][4], alo[2][4];
#pragma unroll
  for (int set = 0; set < 2; ++set) {
    const int hwl = w * 32 + set * 16 + l15;
    float xs = 0.f;
#pragma unroll
    for (int s = 0; s < 4; ++s) {
      const int dbase = s * 32 + quad * 8;
      FragU fh, fl;
#pragma unroll
      for (int j = 0; j < 8; ++j) {
        float v = xbase[(size_t)(dbase + j) * 1024 + hwl];
        xs = fmaf(v, v, xs);
        float hif;
        fh.u16[j] = bf16_hi_rne(v, &hif);
        fl.u16[j] = bf16_rne(v - hif);
      }
      ahi[set][s] = fh.v;
      alo[set][s] = fl.v;
    }
    xs += __shfl_xor(xs, 16, 64);
    xs += __shfl_xor(xs, 32, 64);
    if (lane < 16) dist[w * 32 + set * 16 + l15] = xs;
  }

  uint best[8], best2[8];
#pragma unroll
  for (int i = 0; i < 8; ++i) { best[i] = 0u; best2[i] = 0u; }

  // ---- barrier-free K loop: 64 tiles of 16 codes ----
#pragma unroll 1
  for (int t = 0; t < 64; ++t) {
    const uint tinv = (uint)(63 - t);
    float en = enB[t * 16 + l15];
    const uint4* pb = gB + t * 512 + lane;
    bf16x8 bh[4], bl[4];
#pragma unroll
    for (int s = 0; s < 4; ++s) {
      FragU fh, fl;
      fh.q = pb[s * 128];
      fl.q = pb[s * 128 + 64];
      bh[s] = fh.v;
      bl[s] = fl.v;
    }
    f32x4 acc[2];
#pragma unroll
    for (int set = 0; set < 2; ++set) acc[set] = (f32x4){0.f, 0.f, 0.f, 0.f};
#pragma unroll
    for (int s = 0; s < 4; ++s) {
#pragma unroll
      for (int set = 0; set < 2; ++set)
        acc[set] = __builtin_amdgcn_mfma_f32_16x16x32_bf16(ahi[set][s], bh[s], acc[set], 0, 0, 0);
#pragma unroll
      for (int set = 0; set < 2; ++set)
        acc[set] = __builtin_amdgcn_mfma_f32_16x16x32_bf16(ahi[set][s], bl[s], acc[set], 0, 0, 0);
#pragma unroll
      for (int set = 0; set < 2; ++set)
        acc[set] = __builtin_amdgcn_mfma_f32_16x16x32_bf16(alo[set][s], bh[s], acc[set], 0, 0, 0);
    }
    // packed top-2: key = (bits(score+en) & ~63) | (63-t)
#pragma unroll
    for (int set = 0; set < 2; ++set) {
#pragma unroll
      for (int r = 0; r < 4; ++r) {
        float sb = acc[set][r] + en;
        uint key = (__float_as_uint(sb) & 0xFFFFFFC0u) | tinv;
        uint ob = best[set * 4 + r];
        uint mn = key < ob ? key : ob;
        best[set * 4 + r] = key > ob ? key : ob;
        if (mn > best2[set * 4 + r]) best2[set * 4 + r] = mn;
      }
    }
  }

  // ---- cross-lane reduce over the 16 code-sublanes ----
  __syncthreads();  // dist[] published; Lds reuse begins
#pragma unroll
  for (int set = 0; set < 2; ++set) {
#pragma unroll
    for (int r = 0; r < 4; ++r) {
      int m = w * 32 + set * 16 + quad * 4 + r;
      sS[m * 17 + l15] = best[set * 4 + r];
      sS2[m * 17 + l15] = best2[set * 4 + r];
    }
  }
  __syncthreads();

  if (tid < 128) {
    int m = tid;
    uint g1 = 0, g2 = 0;
    int gi = 0;
#pragma unroll 4
    for (int li = 0; li < 16; ++li) {
      uint key = sS[m * 17 + li];
      uint sb = key >> 6;
      int kk = (int)(63u - (key & 63u)) * 16 + li;
      if (sb > g1) { g2 = g1; g1 = sb; gi = kk; }
      else {
        if (sb == g1 && kk < gi) gi = kk;
        if (sb > g2) g2 = sb;
      }
      uint sb2 = sS2[m * 17 + li] >> 6;
      if (sb2 > g2) g2 = sb2;
    }
    sIdx[m] = gi;
    float s1f = __uint_as_float(g1 << 6);
    dist[m] = dist[m] - 2.0f * (s1f - SBIAS);
    float gap = s1f - __uint_as_float(g2 << 6);
    if (gap < MARGIN) {
      int pos = atomicAdd(lcnt, 1);
      list[pos] = m;
    }
  }
  __syncthreads();

  // ---- block-cooperative fp64 refine for flagged rows (rare) ----
  const int cnt = *lcnt;
  for (int i = 0; i < cnt; ++i) {
    const int m = list[i];
    if (tid < 128) xrowd[tid] = (double)xbase[(size_t)tid * 1024 + m];
    __syncthreads();
    double bd = 1e300;
    int bk = 0;
#pragma unroll 1
    for (int j = 0; j < 4; ++j) {
      const int k = tid * 4 + j;
      const float4* er = (const float4*)(cbn + (size_t)k * D_);
      double d = 0.0;
#pragma unroll 8
      for (int c4 = 0; c4 < 32; ++c4) {
        float4 e = er[c4];
        double d0 = xrowd[c4 * 4 + 0] - (double)e.x;
        double d1 = xrowd[c4 * 4 + 1] - (double)e.y;
        double d2 = xrowd[c4 * 4 + 2] - (double)e.z;
        double d3 = xrowd[c4 * 4 + 3] - (double)e.w;
        d = fma(d0, d0, d);
        d = fma(d1, d1, d);
        d = fma(d2, d2, d);
        d = fma(d3, d3, d);
      }
      if (d < bd) { bd = d; bk = k; }
    }
#pragma unroll
    for (int off = 32; off; off >>= 1) {
      double od = __shfl_down(bd, off, 64);
      int ok = __shfl_down(bk, off, 64);
      if (od < bd || (od == bd && ok < bk)) { bd = od; bk = ok; }
    }
    if (lane == 0) { rd[w] = bd; rk[w] = bk; }
    __syncthreads();
    if (tid == 0) {
      double gb = rd[0];
      int gk = rk[0];
      for (int t = 1; t < 4; ++t)
        if (rd[t] < gb || (rd[t] == gb && rk[t] < gk)) { gb = rd[t]; gk = rk[t]; }
      sIdx[m] = gk;
      dist[m] = (float)gb;
    }
    __syncthreads();
  }

  // ---- indices + histogram + loss ----
  if (tid < 128) {
    int bi = sIdx[tid];
    out[IDX_OFF + (b * 4 + n) * 1024 + hw0 + tid] = (float)bi;
    atomicAdd(ws + WS_CNT + n * K_ + bi, 1.0f);
  }
  float lp = (tid < 128) ? dist[tid] : 0.f;
#pragma unroll
  for (int off = 32; off; off >>= 1) lp += __shfl_down(lp, off, 64);
  if (lane == 0 && w < 2) atomicAdd(ws + WS_LOSS + n, lp);
  __syncthreads();

  // ---- quantized write via LDS-staged gather, 4 d-quarters of 32 ----
  float* out0 = out + (size_t)((b * 4 + n) * 128) * 1024 + hw0;
#pragma unroll 1
  for (int q = 0; q < 4; ++q) {
    const int m = tid & 127, part = tid >> 7;
    const float* src = cbn + (size_t)sIdx[m] * D_ + q * 32 + part * 16;
#pragma unroll
    for (int i = 0; i < 4; ++i) {
      float4 v = ((const float4*)src)[i];
      int dl = part * 16 + i * 4;
      Qs[(dl + 0) * 128 + m] = v.x;
      Qs[(dl + 1) * 128 + m] = v.y;
      Qs[(dl + 2) * 128 + m] = v.z;
      Qs[(dl + 3) * 128 + m] = v.w;
    }
    __syncthreads();
#pragma unroll
    for (int it = 0; it < 4; ++it) {
      int e = it * 256 + tid;
      int m4 = (e & 31) * 4;
      int dl = e >> 5;
      float4 v = *(float4*)(Qs + dl * 128 + m4);
      *(float4*)(out0 + (size_t)(q * 32 + dl) * 1024 + m4) = v;
    }
    __syncthreads();
  }
}

// --- finalize: loss scale + perplexity ---
__global__ void vq_finalize(const float* __restrict__ ws, float* __restrict__ out) {
  int n = blockIdx.x;
  int t = threadIdx.x;
  const float* counts = ws + WS_CNT + n * K_;
  float s = 0.f;
  for (int k = t; k < K_; k += 256) {
    float p = counts[k] * (1.0f / 32768.0f);
    s += p * logf(p + 1e-10f);
  }
  __shared__ float red[4];
#pragma unroll
  for (int off = 32; off; off >>= 1) s += __shfl_down(s, off, 64);
  if ((t & 63) == 0) red[t >> 6] = s;
  __syncthreads();
  if (t == 0) {
    s = red[0] + red[1] + red[2] + red[3];
    out[PERP_OFF + n] = expf(-s);
    out[LOSS_OFF + n] = 1.25f * ws[WS_LOSS + n] / 4194304.0f;
  }
}

extern "C" void kernel_launch(void* const* d_in, const int* in_sizes, int n_in,
                              void* d_out, int out_size, void* d_ws, size_t ws_size,
                              hipStream_t stream) {
  const float* x = (const float*)d_in[0];
  const float* cb = (const float*)d_in[1];
  float* out = (float*)d_out;
  float* ws = (float*)d_ws;
  vq_pack<<<257, 256, 0, stream>>>(cb, ws);
  vq_main<<<1024, 256, 0, stream>>>(x, cb, ws, out);
  vq_finalize<<<4, 256, 0, stream>>>(ws, out);
}

// Round 7
// 296.882 us; speedup vs baseline: 1.0443x; 1.0443x over previous
//
#include <hip/hip_runtime.h>

#define B_ 32
#define N_ 4
#define D_ 128
#define M_ 32768
#define K_ 1024

#define IDX_OFF 16777216
#define LOSS_OFF 16908288
#define PERP_OFF 16908292

// ws float-index layout
#define WS_LOSS 0
#define WS_CNT 1024
#define WS_ENORM 8192
#define WS_BPACK_F 16384        // packed split-bf16 codebook: 4 layers * 512KB = 2MB
#define BPACK_LAYER_US 262144
#define WS_IDX 540672           // 131072 ints (per-row argmin), after bpack

#define SBIAS 384.0f
#define MARGIN 0.012f

typedef __bf16 bf16x8 __attribute__((ext_vector_type(8)));
typedef float f32x4 __attribute__((ext_vector_type(4)));

union FragU {
  bf16x8 v;
  ushort u16[8];
  uint4 q;
};

__device__ __forceinline__ ushort bf16_hi_rne(float f, float* hif) {
  uint u = __float_as_uint(f);
  uint r = (u + 0x7fffu + ((u >> 16) & 1u)) >> 16;
  *hif = __uint_as_float(r << 16);
  return (ushort)r;
}
__device__ __forceinline__ ushort bf16_rne(float f) {
  uint u = __float_as_uint(f);
  return (ushort)((u + 0x7fffu + ((u >> 16) & 1u)) >> 16);
}

__device__ __forceinline__ void gload_lds16(const void* g, void* l) {
  __builtin_amdgcn_global_load_lds(
      (const __attribute__((address_space(1))) unsigned int*)g,
      (__attribute__((address_space(3))) unsigned int*)l, 16, 0, 0);
}

// --- prep: coalesced pack (LDS bounce) + enorm + zero accumulators ---
__global__ __launch_bounds__(256) void vq_pack(const float* __restrict__ cb,
                                               float* __restrict__ ws) {
  __shared__ ushort Hs[16 * 132];
  __shared__ ushort Ls[16 * 132];
  __shared__ float Ps[256];
  int blk = blockIdx.x, tid = threadIdx.x;
  if (blk < 256) {
    int n = blk >> 6, tile = blk & 63;
    int c = tid >> 4, f = tid & 15;
    const float* src = cb + ((size_t)(n * K_ + tile * 16 + c)) * D_ + f * 8;
    float4 v0 = *(const float4*)src;
    float4 v1 = *(const float4*)(src + 4);
    float v[8] = {v0.x, v0.y, v0.z, v0.w, v1.x, v1.y, v1.z, v1.w};
    float ss = 0.f;
#pragma unroll
    for (int j = 0; j < 8; ++j) {
      float hif;
      Hs[c * 132 + f * 8 + j] = bf16_hi_rne(v[j], &hif);
      Ls[c * 132 + f * 8 + j] = bf16_rne(v[j] - hif);
      ss = fmaf(v[j], v[j], ss);
    }
    Ps[c * 16 + f] = ss;
    __syncthreads();
    if (tid < 16) {
      float s = 0.f;
#pragma unroll
      for (int j = 0; j < 16; ++j) s += Ps[tid * 16 + j];
      ws[WS_ENORM + n * K_ + tile * 16 + tid] = SBIAS - 0.5f * s;
    }
    int s = tid >> 6, lane = tid & 63;
    int code = lane & 15, dstart = s * 32 + ((lane >> 4) << 3);
    FragU fh, fl;
#pragma unroll
    for (int j = 0; j < 8; ++j) {
      fh.u16[j] = Hs[code * 132 + dstart + j];
      fl.u16[j] = Ls[code * 132 + dstart + j];
    }
    ushort* dst = (ushort*)(ws + WS_BPACK_F) + (size_t)n * BPACK_LAYER_US +
                  ((size_t)(tile * 4 + s) * 2) * 512 + lane * 8;
    *(uint4*)dst = fh.q;
    *(uint4*)(dst + 512) = fl.q;
  } else {
#pragma unroll
    for (int i = 0; i < 20; ++i) ws[i * 256 + tid] = 0.f;
  }
}

// --- scoring: LDS-staged split-bf16 MFMA + deferred top-2 + refine ---
__global__ __launch_bounds__(256, 4) void vq_score(const float* __restrict__ x,
                                                   const float* __restrict__ cb,
                                                   float* __restrict__ ws,
                                                   float* __restrict__ out) {
  __shared__ alignas(16) ushort Bsm[18432];  // 36 KB: 2x16KB dbuf + 4KB ext
  const int tid = threadIdx.x;
  const int bid = blockIdx.x;
  const int n = bid >> 8;
  const int mblk = bid & 255;
  const int b = mblk >> 3;
  const int hw0 = (mblk & 7) << 7;

  const int lane = tid & 63, w = tid >> 6;
  const int quad = lane >> 4, l15 = lane & 15;

  const float* xbase = x + (size_t)((b * 4 + n) * 128) * 1024 + hw0;
  const float* cbn = cb + (size_t)n * K_ * D_;
  const float* enB = ws + WS_ENORM + n * K_;
  const uint4* gsrc = (const uint4*)((ushort*)(ws + WS_BPACK_F) + (size_t)n * BPACK_LAYER_US);
  uint4* Bsm4 = (uint4*)Bsm;

  // ext LDS (beyond the 32KB dbuf)
  char* ext = (char*)Bsm + 32768;
  int* sIdx = (int*)ext;                  // [128]
  float* dist = (float*)(ext + 512);      // [128]
  int* list = (int*)(ext + 1024);         // [128]
  int* lcnt = (int*)(ext + 1536);         // [1]
  double* xrowd = (double*)(ext + 1544);  // [128]
  double* rd = (double*)(ext + 2568);     // [4]
  int* rk = (int*)(ext + 2600);           // [4]

  if (tid == 0) *lcnt = 0;

  // ---- A fragments: 32 rows/wave, 2 sets of 16; + ||x||^2 ----
  bf16x8 ahi[2][4], alo[2][4];
#pragma unroll
  for (int set = 0; set < 2; ++set) {
    const int hwl = w * 32 + set * 16 + l15;
    float xs = 0.f;
#pragma unroll
    for (int s = 0; s < 4; ++s) {
      const int dbase = s * 32 + quad * 8;
      FragU fh, fl;
#pragma unroll
      for (int j = 0; j < 8; ++j) {
        float v = xbase[(size_t)(dbase + j) * 1024 + hwl];
        xs = fmaf(v, v, xs);
        float hif;
        fh.u16[j] = bf16_hi_rne(v, &hif);
        fl.u16[j] = bf16_rne(v - hif);
      }
      ahi[set][s] = fh.v;
      alo[set][s] = fl.v;
    }
    xs += __shfl_xor(xs, 16, 64);
    xs += __shfl_xor(xs, 32, 64);
    if (lane < 16) dist[w * 32 + set * 16 + l15] = xs;
  }

  uint best[8], best2[8], keyp[8];
#pragma unroll
  for (int i = 0; i < 8; ++i) { best[i] = 0u; best2[i] = 0u; keyp[i] = 0u; }

  // prologue: stage chunk 0 (16KB)
#pragma unroll
  for (int i = 0; i < 4; ++i)
    gload_lds16(gsrc + i * 256 + w * 64 + lane, Bsm4 + i * 256 + w * 64);

#pragma unroll 1
  for (int c = 0; c < 32; ++c) {
    __syncthreads();  // publishes stage(c)
    if (c < 31) {
      const uint4* src = gsrc + (c + 1) * 1024;
      uint4* dst = Bsm4 + ((c + 1) & 1) * 1024;
#pragma unroll
      for (int i = 0; i < 4; ++i)
        gload_lds16(src + i * 256 + w * 64 + lane, dst + i * 256 + w * 64);
    }
    const ushort* Bcur = Bsm + (c & 1) * 8192;
#pragma unroll
    for (int tin = 0; tin < 2; ++tin) {
      const int t = c * 2 + tin;
      const uint tinv = (uint)(63 - t);
      float en = enB[t * 16 + l15];
      bf16x8 bh[4], bl[4];
#pragma unroll
      for (int s = 0; s < 4; ++s) {
        const ushort* p = Bcur + ((tin * 4 + s) * 2) * 512 + lane * 8;
        bh[s] = ((const FragU*)p)->v;
        bl[s] = ((const FragU*)(p + 512))->v;
      }
      f32x4 acc[2];
#pragma unroll
      for (int set = 0; set < 2; ++set) acc[set] = (f32x4){0.f, 0.f, 0.f, 0.f};
#pragma unroll
      for (int s = 0; s < 4; ++s) {
#pragma unroll
        for (int set = 0; set < 2; ++set)
          acc[set] = __builtin_amdgcn_mfma_f32_16x16x32_bf16(ahi[set][s], bh[s], acc[set], 0, 0, 0);
#pragma unroll
        for (int set = 0; set < 2; ++set)
          acc[set] = __builtin_amdgcn_mfma_f32_16x16x32_bf16(ahi[set][s], bl[s], acc[set], 0, 0, 0);
#pragma unroll
        for (int set = 0; set < 2; ++set)
          acc[set] = __builtin_amdgcn_mfma_f32_16x16x32_bf16(alo[set][s], bh[s], acc[set], 0, 0, 0);
      }
      // deferred merge of PREVIOUS tile's keys (independent of in-flight acc)
#pragma unroll
      for (int i = 0; i < 8; ++i) {
        uint k = keyp[i], ob = best[i];
        uint mn = k < ob ? k : ob;
        best[i] = k > ob ? k : ob;
        if (mn > best2[i]) best2[i] = mn;
      }
      // pack this tile's keys (depends on acc)
#pragma unroll
      for (int set = 0; set < 2; ++set) {
#pragma unroll
        for (int r = 0; r < 4; ++r) {
          float sb = acc[set][r] + en;
          keyp[set * 4 + r] = (__float_as_uint(sb) & 0xFFFFFFC0u) | tinv;
        }
      }
    }
  }
  // final deferred merge
#pragma unroll
  for (int i = 0; i < 8; ++i) {
    uint k = keyp[i], ob = best[i];
    uint mn = k < ob ? k : ob;
    best[i] = k > ob ? k : ob;
    if (mn > best2[i]) best2[i] = mn;
  }
  __syncthreads();  // dbuf free; overlay

  uint* sS = (uint*)Bsm;                     // [128][17]
  uint* sS2 = (uint*)((char*)Bsm + 8704);    // [128][17]
#pragma unroll
  for (int set = 0; set < 2; ++set) {
#pragma unroll
    for (int r = 0; r < 4; ++r) {
      int m = w * 32 + set * 16 + quad * 4 + r;
      sS[m * 17 + l15] = best[set * 4 + r];
      sS2[m * 17 + l15] = best2[set * 4 + r];
    }
  }
  __syncthreads();

  if (tid < 128) {
    int m = tid;
    uint g1 = 0, g2 = 0;
    int gi = 0;
#pragma unroll 4
    for (int li = 0; li < 16; ++li) {
      uint key = sS[m * 17 + li];
      uint sb = key >> 6;
      int kk = (int)(63u - (key & 63u)) * 16 + li;
      if (sb > g1) { g2 = g1; g1 = sb; gi = kk; }
      else {
        if (sb == g1 && kk < gi) gi = kk;
        if (sb > g2) g2 = sb;
      }
      uint sb2 = sS2[m * 17 + li] >> 6;
      if (sb2 > g2) g2 = sb2;
    }
    sIdx[m] = gi;
    float s1f = __uint_as_float(g1 << 6);
    dist[m] = dist[m] - 2.0f * (s1f - SBIAS);
    float gap = s1f - __uint_as_float(g2 << 6);
    if (gap < MARGIN) {
      int pos = atomicAdd(lcnt, 1);
      list[pos] = m;
    }
  }
  __syncthreads();

  // ---- block-cooperative fp64 refine for flagged rows (rare) ----
  const int cnt = *lcnt;
  for (int i = 0; i < cnt; ++i) {
    const int m = list[i];
    if (tid < 128) xrowd[tid] = (double)xbase[(size_t)tid * 1024 + m];
    __syncthreads();
    double bd = 1e300;
    int bk = 0;
#pragma unroll 1
    for (int j = 0; j < 4; ++j) {
      const int k = tid * 4 + j;
      const float4* er = (const float4*)(cbn + (size_t)k * D_);
      double d = 0.0;
#pragma unroll 8
      for (int c4 = 0; c4 < 32; ++c4) {
        float4 e = er[c4];
        double d0 = xrowd[c4 * 4 + 0] - (double)e.x;
        double d1 = xrowd[c4 * 4 + 1] - (double)e.y;
        double d2 = xrowd[c4 * 4 + 2] - (double)e.z;
        double d3 = xrowd[c4 * 4 + 3] - (double)e.w;
        d = fma(d0, d0, d);
        d = fma(d1, d1, d);
        d = fma(d2, d2, d);
        d = fma(d3, d3, d);
      }
      if (d < bd) { bd = d; bk = k; }
    }
#pragma unroll
    for (int off = 32; off; off >>= 1) {
      double od = __shfl_down(bd, off, 64);
      int ok = __shfl_down(bk, off, 64);
      if (od < bd || (od == bd && ok < bk)) { bd = od; bk = ok; }
    }
    if (lane == 0) { rd[w] = bd; rk[w] = bk; }
    __syncthreads();
    if (tid == 0) {
      double gb = rd[0];
      int gk = rk[0];
      for (int t = 1; t < 4; ++t)
        if (rd[t] < gb || (rd[t] == gb && rk[t] < gk)) { gb = rd[t]; gk = rk[t]; }
      sIdx[m] = gk;
      dist[m] = (float)gb;
    }
    __syncthreads();
  }

  // ---- indices (out + ws) + histogram + loss ----
  if (tid < 128) {
    int bi = sIdx[tid];
    int gpos = (b * 4 + n) * 1024 + hw0 + tid;
    out[IDX_OFF + gpos] = (float)bi;
    ((int*)(ws + WS_IDX))[gpos] = bi;
    atomicAdd(ws + WS_CNT + n * K_ + bi, 1.0f);
  }
  float lp = (tid < 128) ? dist[tid] : 0.f;
#pragma unroll
  for (int off = 32; off; off >>= 1) lp += __shfl_down(lp, off, 64);
  if (lane == 0 && w < 2) atomicAdd(ws + WS_LOSS + n, lp);
}

// --- output: gather codebook rows -> quantized_cat (LDS transpose) ---
__global__ __launch_bounds__(256) void vq_write(const float* __restrict__ cb,
                                                const float* __restrict__ ws,
                                                float* __restrict__ out) {
  __shared__ float Qs[32 * 128];  // 16 KB
  __shared__ int sIdx[128];
  const int tid = threadIdx.x;
  const int bid = blockIdx.x;
  const int n = bid >> 8;
  const int mblk = bid & 255;
  const int b = mblk >> 3;
  const int hw0 = (mblk & 7) << 7;
  const float* cbn = cb + (size_t)n * K_ * D_;
  const int* ig = (const int*)(ws + WS_IDX) + (b * 4 + n) * 1024 + hw0;
  if (tid < 128) sIdx[tid] = ig[tid];
  __syncthreads();
  float* out0 = out + (size_t)((b * 4 + n) * 128) * 1024 + hw0;
#pragma unroll 1
  for (int q = 0; q < 4; ++q) {
    const int m = tid & 127, part = tid >> 7;
    const float* src = cbn + (size_t)sIdx[m] * D_ + q * 32 + part * 16;
#pragma unroll
    for (int i = 0; i < 4; ++i) {
      float4 v = ((const float4*)src)[i];
      int dl = part * 16 + i * 4;
      Qs[(dl + 0) * 128 + m] = v.x;
      Qs[(dl + 1) * 128 + m] = v.y;
      Qs[(dl + 2) * 128 + m] = v.z;
      Qs[(dl + 3) * 128 + m] = v.w;
    }
    __syncthreads();
#pragma unroll
    for (int it = 0; it < 4; ++it) {
      int e = it * 256 + tid;
      int m4 = (e & 31) * 4;
      int dl = e >> 5;
      float4 v = *(float4*)(Qs + dl * 128 + m4);
      *(float4*)(out0 + (size_t)(q * 32 + dl) * 1024 + m4) = v;
    }
    __syncthreads();
  }
}

// --- finalize: loss scale + perplexity ---
__global__ void vq_finalize(const float* __restrict__ ws, float* __restrict__ out) {
  int n = blockIdx.x;
  int t = threadIdx.x;
  const float* counts = ws + WS_CNT + n * K_;
  float s = 0.f;
  for (int k = t; k < K_; k += 256) {
    float p = counts[k] * (1.0f / 32768.0f);
    s += p * logf(p + 1e-10f);
  }
  __shared__ float red[4];
#pragma unroll
  for (int off = 32; off; off >>= 1) s += __shfl_down(s, off, 64);
  if ((t & 63) == 0) red[t >> 6] = s;
  __syncthreads();
  if (t == 0) {
    s = red[0] + red[1] + red[2] + red[3];
    out[PERP_OFF + n] = expf(-s);
    out[LOSS_OFF + n] = 1.25f * ws[WS_LOSS + n] / 4194304.0f;
  }
}

extern "C" void kernel_launch(void* const* d_in, const int* in_sizes, int n_in,
                              void* d_out, int out_size, void* d_ws, size_t ws_size,
                              hipStream_t stream) {
  const float* x = (const float*)d_in[0];
  const float* cb = (const float*)d_in[1];
  float* out = (float*)d_out;
  float* ws = (float*)d_ws;
  vq_pack<<<257, 256, 0, stream>>>(cb, ws);
  vq_score<<<1024, 256, 0, stream>>>(x, cb, ws, out);
  vq_write<<<1024, 256, 0, stream>>>(cb, ws, out);
  vq_finalize<<<4, 256, 0, stream>>>(ws, out);
}

// Round 8
// 296.531 us; speedup vs baseline: 1.0455x; 1.0012x over previous
//
#include <hip/hip_runtime.h>

#define B_ 32
#define N_ 4
#define D_ 128
#define M_ 32768
#define K_ 1024

#define IDX_OFF 16777216
#define LOSS_OFF 16908288
#define PERP_OFF 16908292

// ws float-index layout
#define WS_LOSS 0
#define WS_CNT 1024
#define WS_ENORM 8192
#define WS_BPACK_F 16384        // packed split-bf16 codebook: 4 layers * 512KB = 2MB
#define BPACK_LAYER_US 262144

#define SBIAS 384.0f
#define MARGIN 0.012f

typedef __bf16 bf16x8 __attribute__((ext_vector_type(8)));
typedef float f32x4 __attribute__((ext_vector_type(4)));

union FragU {
  bf16x8 v;
  ushort u16[8];
  uint4 q;
};

__device__ __forceinline__ ushort bf16_hi_rne(float f, float* hif) {
  uint u = __float_as_uint(f);
  uint r = (u + 0x7fffu + ((u >> 16) & 1u)) >> 16;
  *hif = __uint_as_float(r << 16);
  return (ushort)r;
}
__device__ __forceinline__ ushort bf16_rne(float f) {
  uint u = __float_as_uint(f);
  return (ushort)((u + 0x7fffu + ((u >> 16) & 1u)) >> 16);
}

__device__ __forceinline__ void gload_lds16(const void* g, void* l) {
  __builtin_amdgcn_global_load_lds(
      (const __attribute__((address_space(1))) unsigned int*)g,
      (__attribute__((address_space(3))) unsigned int*)l, 16, 0, 0);
}

// --- prep: coalesced pack (LDS bounce) + enorm + zero accumulators ---
__global__ __launch_bounds__(256) void vq_pack(const float* __restrict__ cb,
                                               float* __restrict__ ws) {
  __shared__ ushort Hs[16 * 132];
  __shared__ ushort Ls[16 * 132];
  __shared__ float Ps[256];
  int blk = blockIdx.x, tid = threadIdx.x;
  if (blk < 256) {
    int n = blk >> 6, tile = blk & 63;
    int c = tid >> 4, f = tid & 15;
    const float* src = cb + ((size_t)(n * K_ + tile * 16 + c)) * D_ + f * 8;
    float4 v0 = *(const float4*)src;
    float4 v1 = *(const float4*)(src + 4);
    float v[8] = {v0.x, v0.y, v0.z, v0.w, v1.x, v1.y, v1.z, v1.w};
    float ss = 0.f;
#pragma unroll
    for (int j = 0; j < 8; ++j) {
      float hif;
      Hs[c * 132 + f * 8 + j] = bf16_hi_rne(v[j], &hif);
      Ls[c * 132 + f * 8 + j] = bf16_rne(v[j] - hif);
      ss = fmaf(v[j], v[j], ss);
    }
    Ps[c * 16 + f] = ss;
    __syncthreads();
    if (tid < 16) {
      float s = 0.f;
#pragma unroll
      for (int j = 0; j < 16; ++j) s += Ps[tid * 16 + j];
      ws[WS_ENORM + n * K_ + tile * 16 + tid] = SBIAS - 0.5f * s;
    }
    int s = tid >> 6, lane = tid & 63;
    int code = lane & 15, dstart = s * 32 + ((lane >> 4) << 3);
    FragU fh, fl;
#pragma unroll
    for (int j = 0; j < 8; ++j) {
      fh.u16[j] = Hs[code * 132 + dstart + j];
      fl.u16[j] = Ls[code * 132 + dstart + j];
    }
    ushort* dst = (ushort*)(ws + WS_BPACK_F) + (size_t)n * BPACK_LAYER_US +
                  ((size_t)(tile * 4 + s) * 2) * 512 + lane * 8;
    *(uint4*)dst = fh.q;
    *(uint4*)(dst + 512) = fl.q;
  } else {
#pragma unroll
    for (int i = 0; i < 20; ++i) ws[i * 256 + tid] = 0.f;
  }
}

// --- main: fused score + argmin + refine + outputs; 512 threads/block ---
__global__ __launch_bounds__(512, 4) void vq_main(const float* __restrict__ x,
                                                  const float* __restrict__ cb,
                                                  float* __restrict__ ws,
                                                  float* __restrict__ out) {
  __shared__ alignas(16) char Lds[37120];  // [0,32768): dbuf / Qs(32896) ; [32896,...): ext
  const int tid = threadIdx.x;
  const int bid = blockIdx.x;
  const int n = bid >> 7;          // 4 layers x 128 m-tiles of 256 rows
  const int mblk = bid & 127;
  const int b = mblk >> 2;
  const int hw0 = (mblk & 3) << 8;

  const int lane = tid & 63, w = tid >> 6;     // 8 waves
  const int quad = lane >> 4, l15 = lane & 15;

  const float* xbase = x + (size_t)((b * 4 + n) * 128) * 1024 + hw0;
  const float* cbn = cb + (size_t)n * K_ * D_;
  const float* enB = ws + WS_ENORM + n * K_;
  const uint4* gsrc = (const uint4*)((ushort*)(ws + WS_BPACK_F) + (size_t)n * BPACK_LAYER_US);

  ushort* Bsm = (ushort*)Lds;
  uint4* Bsm4 = (uint4*)Lds;
  // ext region (never overlaps dbuf or Qs)
  char* ext = Lds + 32896;
  int* sIdx = (int*)ext;                   // [256]
  float* dist = (float*)(ext + 1024);      // [256]
  int* list = (int*)(ext + 2048);          // [256]
  int* lcnt = (int*)(ext + 3072);          // [1]
  double* xrowd = (double*)(ext + 3080);   // [128]
  double* rd = (double*)(ext + 4104);      // [8]
  int* rk = (int*)(ext + 4168);            // [8]
  float* Qs = (float*)Lds;                 // [32][257] = 32896 B (after K-loop)

  if (tid == 0) *lcnt = 0;

  // ---- A fragments: 32 rows/wave, 2 sets of 16; + ||x||^2 ----
  bf16x8 ahi[2][4], alo[2][4];
#pragma unroll
  for (int set = 0; set < 2; ++set) {
    const int hwl = w * 32 + set * 16 + l15;
    float xs = 0.f;
#pragma unroll
    for (int s = 0; s < 4; ++s) {
      const int dbase = s * 32 + quad * 8;
      FragU fh, fl;
#pragma unroll
      for (int j = 0; j < 8; ++j) {
        float v = xbase[(size_t)(dbase + j) * 1024 + hwl];
        xs = fmaf(v, v, xs);
        float hif;
        fh.u16[j] = bf16_hi_rne(v, &hif);
        fl.u16[j] = bf16_rne(v - hif);
      }
      ahi[set][s] = fh.v;
      alo[set][s] = fl.v;
    }
    xs += __shfl_xor(xs, 16, 64);
    xs += __shfl_xor(xs, 32, 64);
    if (lane < 16) dist[w * 32 + set * 16 + l15] = xs;  // ||x||^2 per row
  }

  uint best[8], best2[8], keyp[8];
#pragma unroll
  for (int i = 0; i < 8; ++i) { best[i] = 0u; best2[i] = 0u; keyp[i] = 0u; }

  // prologue: stage chunk 0 (16KB; 8 waves x 2 x 64 lanes x 16B)
#pragma unroll
  for (int i = 0; i < 2; ++i)
    gload_lds16(gsrc + w * 128 + i * 64 + lane, Bsm4 + w * 128 + i * 64);

#pragma unroll 1
  for (int c = 0; c < 32; ++c) {
    __syncthreads();  // publishes stage(c)
    if (c < 31) {
      const uint4* src = gsrc + (c + 1) * 1024;
      uint4* dst = Bsm4 + ((c + 1) & 1) * 1024;
#pragma unroll
      for (int i = 0; i < 2; ++i)
        gload_lds16(src + w * 128 + i * 64 + lane, dst + w * 128 + i * 64);
    }
    const ushort* Bcur = Bsm + (c & 1) * 8192;
#pragma unroll
    for (int tin = 0; tin < 2; ++tin) {
      const int t = c * 2 + tin;
      const uint tinv = (uint)(63 - t);
      float en = enB[t * 16 + l15];
      bf16x8 bh[4], bl[4];
#pragma unroll
      for (int s = 0; s < 4; ++s) {
        const ushort* p = Bcur + ((tin * 4 + s) * 2) * 512 + lane * 8;
        bh[s] = ((const FragU*)p)->v;
        bl[s] = ((const FragU*)(p + 512))->v;
      }
      f32x4 acc[2];
#pragma unroll
      for (int set = 0; set < 2; ++set) acc[set] = (f32x4){0.f, 0.f, 0.f, 0.f};
#pragma unroll
      for (int s = 0; s < 4; ++s) {
#pragma unroll
        for (int set = 0; set < 2; ++set)
          acc[set] = __builtin_amdgcn_mfma_f32_16x16x32_bf16(ahi[set][s], bh[s], acc[set], 0, 0, 0);
#pragma unroll
        for (int set = 0; set < 2; ++set)
          acc[set] = __builtin_amdgcn_mfma_f32_16x16x32_bf16(ahi[set][s], bl[s], acc[set], 0, 0, 0);
#pragma unroll
        for (int set = 0; set < 2; ++set)
          acc[set] = __builtin_amdgcn_mfma_f32_16x16x32_bf16(alo[set][s], bh[s], acc[set], 0, 0, 0);
      }
      // deferred merge of previous tile's keys (independent of in-flight acc)
#pragma unroll
      for (int i = 0; i < 8; ++i) {
        uint k = keyp[i], ob = best[i];
        uint mn = k < ob ? k : ob;
        best[i] = k > ob ? k : ob;
        if (mn > best2[i]) best2[i] = mn;
      }
#pragma unroll
      for (int set = 0; set < 2; ++set) {
#pragma unroll
        for (int r = 0; r < 4; ++r) {
          float sb = acc[set][r] + en;
          keyp[set * 4 + r] = (__float_as_uint(sb) & 0xFFFFFFC0u) | tinv;
        }
      }
    }
  }
#pragma unroll
  for (int i = 0; i < 8; ++i) {
    uint k = keyp[i], ob = best[i];
    uint mn = k < ob ? k : ob;
    best[i] = k > ob ? k : ob;
    if (mn > best2[i]) best2[i] = mn;
  }

  // ---- barrier-free top-2 reduce across the 16 code-sublanes (shfl butterfly) ----
  uint pre[8];
#pragma unroll
  for (int i = 0; i < 8; ++i) pre[i] = best[i];
#pragma unroll
  for (int off = 1; off < 16; off <<= 1) {
#pragma unroll
    for (int i = 0; i < 8; ++i) {
      uint o1 = __shfl_xor(best[i], off, 16);
      uint o2 = __shfl_xor(best2[i], off, 16);
      uint mn = best[i] < o1 ? best[i] : o1;
      best[i] = best[i] > o1 ? best[i] : o1;
      uint mx2 = best2[i] > o2 ? best2[i] : o2;
      best2[i] = mn > mx2 ? mn : mx2;
    }
  }
  // winner sublane via ballot; lanes with l15==0 publish their 8 rows
#pragma unroll
  for (int i = 0; i < 8; ++i) {
    bool hit = (pre[i] == best[i]);
    unsigned long long bal = __ballot(hit);
    if (l15 == 0) {
      uint grp = (uint)(bal >> (quad * 16)) & 0xFFFFu;
      int wl = __builtin_ctz(grp);
      int t = 63 - (int)(best[i] & 63u);
      int m = w * 32 + (i >> 2) * 16 + quad * 4 + (i & 3);
      sIdx[m] = t * 16 + wl;
      float s1f = __uint_as_float(best[i] & 0xFFFFFFC0u);
      float s2f = __uint_as_float(best2[i] & 0xFFFFFFC0u);
      dist[m] = dist[m] - 2.0f * (s1f - SBIAS);
      if (s1f - s2f < MARGIN) {
        int pos = atomicAdd(lcnt, 1);
        list[pos] = m;
      }
    }
  }
  __syncthreads();

  // ---- block-cooperative fp64 refine for flagged rows (rare) ----
  const int cnt = *lcnt;
  for (int i = 0; i < cnt; ++i) {
    const int m = list[i];
    if (tid < 128) xrowd[tid] = (double)xbase[(size_t)tid * 1024 + m];
    __syncthreads();
    double bd = 1e300;
    int bk = 0;
#pragma unroll 1
    for (int j = 0; j < 2; ++j) {
      const int k = tid * 2 + j;
      const float4* er = (const float4*)(cbn + (size_t)k * D_);
      double d = 0.0;
#pragma unroll 8
      for (int c4 = 0; c4 < 32; ++c4) {
        float4 e = er[c4];
        double d0 = xrowd[c4 * 4 + 0] - (double)e.x;
        double d1 = xrowd[c4 * 4 + 1] - (double)e.y;
        double d2 = xrowd[c4 * 4 + 2] - (double)e.z;
        double d3 = xrowd[c4 * 4 + 3] - (double)e.w;
        d = fma(d0, d0, d);
        d = fma(d1, d1, d);
        d = fma(d2, d2, d);
        d = fma(d3, d3, d);
      }
      if (d < bd) { bd = d; bk = k; }
    }
#pragma unroll
    for (int off = 32; off; off >>= 1) {
      double od = __shfl_down(bd, off, 64);
      int ok = __shfl_down(bk, off, 64);
      if (od < bd || (od == bd && ok < bk)) { bd = od; bk = ok; }
    }
    if (lane == 0) { rd[w] = bd; rk[w] = bk; }
    __syncthreads();
    if (tid == 0) {
      double gb = rd[0];
      int gk = rk[0];
      for (int t = 1; t < 8; ++t)
        if (rd[t] < gb || (rd[t] == gb && rk[t] < gk)) { gb = rd[t]; gk = rk[t]; }
      sIdx[m] = gk;
      dist[m] = (float)gb;
    }
    __syncthreads();
  }

  // ---- indices + histogram + loss ----
  if (tid < 256) {
    int bi = sIdx[tid];
    out[IDX_OFF + (b * 4 + n) * 1024 + hw0 + tid] = (float)bi;
    atomicAdd(ws + WS_CNT + n * K_ + bi, 1.0f);
  }
  float lp = (tid < 256) ? dist[tid] : 0.f;
#pragma unroll
  for (int off = 32; off; off >>= 1) lp += __shfl_down(lp, off, 64);
  if (lane == 0 && w < 4) atomicAdd(ws + WS_LOSS + n, lp);
  __syncthreads();

  // ---- quantized write via LDS-staged gather, 4 d-quarters of 32 ----
  float* out0 = out + (size_t)((b * 4 + n) * 128) * 1024 + hw0;
#pragma unroll 1
  for (int q = 0; q < 4; ++q) {
    const int m = tid & 255, part = tid >> 8;
    const float* src = cbn + (size_t)sIdx[m] * D_ + q * 32 + part * 16;
#pragma unroll
    for (int i = 0; i < 4; ++i) {
      float4 v = ((const float4*)src)[i];
      int dl = part * 16 + i * 4;
      Qs[(dl + 0) * 257 + m] = v.x;
      Qs[(dl + 1) * 257 + m] = v.y;
      Qs[(dl + 2) * 257 + m] = v.z;
      Qs[(dl + 3) * 257 + m] = v.w;
    }
    __syncthreads();
#pragma unroll
    for (int it = 0; it < 4; ++it) {
      int e = it * 512 + tid;
      int m4 = (e & 63) * 4;
      int dl = e >> 6;
      float4 v = *(float4*)(Qs + dl * 257 + m4);
      *(float4*)(out0 + (size_t)(q * 32 + dl) * 1024 + m4) = v;
    }
    __syncthreads();
  }
}

// --- finalize: loss scale + perplexity ---
__global__ void vq_finalize(const float* __restrict__ ws, float* __restrict__ out) {
  int n = blockIdx.x;
  int t = threadIdx.x;
  const float* counts = ws + WS_CNT + n * K_;
  float s = 0.f;
  for (int k = t; k < K_; k += 256) {
    float p = counts[k] * (1.0f / 32768.0f);
    s += p * logf(p + 1e-10f);
  }
  __shared__ float red[4];
#pragma unroll
  for (int off = 32; off; off >>= 1) s += __shfl_down(s, off, 64);
  if ((t & 63) == 0) red[t >> 6] = s;
  __syncthreads();
  if (t == 0) {
    s = red[0] + red[1] + red[2] + red[3];
    out[PERP_OFF + n] = expf(-s);
    out[LOSS_OFF + n] = 1.25f * ws[WS_LOSS + n] / 4194304.0f;
  }
}

extern "C" void kernel_launch(void* const* d_in, const int* in_sizes, int n_in,
                              void* d_out, int out_size, void* d_ws, size_t ws_size,
                              hipStream_t stream) {
  const float* x = (const float*)d_in[0];
  const float* cb = (const float*)d_in[1];
  float* out = (float*)d_out;
  float* ws = (float*)d_ws;
  vq_pack<<<257, 256, 0, stream>>>(cb, ws);
  vq_main<<<512, 512, 0, stream>>>(x, cb, ws, out);
  vq_finalize<<<4, 256, 0, stream>>>(ws, out);
}